// Round 1
// baseline (5129.710 us; speedup 1.0000x reference)
//
#include <hip/hip_runtime.h>

// GraphSAGE: 3x SAGEConv(mean) + linear head.
// N=100000 nodes, E=3200000 edges, dims 64 -> 64 -> 32 -> 16 -> 1.
// Trick: mean-aggregation is linear, so agg(h) @ Wl == agg(h @ Wl).
// Transform to dout first, then scatter dout-wide rows (dout <= din).

#define NN 100000

// ---------------- degree count + inverse ----------------
__global__ void count_k(const int* __restrict__ dst, int E, int* __restrict__ cnt) {
    int idx = blockIdx.x * blockDim.x + threadIdx.x;
    int stride = gridDim.x * blockDim.x;
    for (int e = idx; e < E; e += stride) atomicAdd(&cnt[dst[e]], 1);
}

__global__ void inv_k(const int* __restrict__ cnt, float* __restrict__ inv, int N) {
    int v = blockIdx.x * blockDim.x + threadIdx.x;
    if (v < N) inv[v] = 1.0f / (float)max(cnt[v], 1);
}

// ---------------- g = h @ W  (N x DIN) @ (DIN x DOUT) ----------------
template <int DIN, int DOUT>
__global__ void transform_k(const float* __restrict__ h, const float* __restrict__ W,
                            float* __restrict__ g, int N) {
    __shared__ float sW[DIN * DOUT];
    for (int i = threadIdx.x; i < DIN * DOUT; i += blockDim.x) sW[i] = W[i];
    __syncthreads();
    int idx = blockIdx.x * blockDim.x + threadIdx.x;
    if (idx >= N * DOUT) return;
    int v = idx / DOUT, j = idx % DOUT;
    const float* hv = h + (size_t)v * DIN;
    float acc = 0.f;
#pragma unroll
    for (int k = 0; k < DIN; ++k) acc = fmaf(hv[k], sW[k * DOUT + j], acc);
    g[idx] = acc;
}

// ---------------- s[dst] += g[src] over edges (float4 granular) ----------------
template <int DOUT>
__global__ void scatter_k(const float* __restrict__ g, const int* __restrict__ src,
                          const int* __restrict__ dst, int E, float* __restrict__ s) {
    constexpr int Q = DOUT / 4;  // float4 chunks per row
    long long total = (long long)E * Q;
    long long idx = (long long)blockIdx.x * blockDim.x + threadIdx.x;
    long long stride = (long long)gridDim.x * blockDim.x;
    for (; idx < total; idx += stride) {
        int e = (int)(idx / Q);
        int q = (int)(idx % Q);
        int sv = src[e], dv = dst[e];
        const float4 gv = *(const float4*)(g + (size_t)sv * DOUT + q * 4);
        float* sp = s + (size_t)dv * DOUT + q * 4;
        atomicAdd(sp + 0, gv.x);
        atomicAdd(sp + 1, gv.y);
        atomicAdd(sp + 2, gv.z);
        atomicAdd(sp + 3, gv.w);
    }
}

// ---------------- out = relu(s*inv + h @ Wr + b) ----------------
template <int DIN, int DOUT>
__global__ void combine_k(const float* __restrict__ s, const float* __restrict__ invc,
                          const float* __restrict__ h, const float* __restrict__ Wr,
                          const float* __restrict__ b, float* __restrict__ out, int N) {
    __shared__ float sW[DIN * DOUT];
    __shared__ float sb[DOUT];
    for (int i = threadIdx.x; i < DIN * DOUT; i += blockDim.x) sW[i] = Wr[i];
    if (threadIdx.x < DOUT) sb[threadIdx.x] = b[threadIdx.x];
    __syncthreads();
    int idx = blockIdx.x * blockDim.x + threadIdx.x;
    if (idx >= N * DOUT) return;
    int v = idx / DOUT, j = idx % DOUT;
    const float* hv = h + (size_t)v * DIN;
    float acc = s[idx] * invc[v] + sb[j];
#pragma unroll
    for (int k = 0; k < DIN; ++k) acc = fmaf(hv[k], sW[k * DOUT + j], acc);
    out[idx] = fmaxf(acc, 0.f);
}

// ---------------- head: out = h3 @ Wc + bc (16 -> 1) ----------------
__global__ void final_k(const float* __restrict__ h, const float* __restrict__ Wc,
                        const float* __restrict__ bc, float* __restrict__ out, int N) {
    int v = blockIdx.x * blockDim.x + threadIdx.x;
    if (v >= N) return;
    float acc = bc[0];
    const float4* hv = (const float4*)(h + (size_t)v * 16);
    const float4* w = (const float4*)Wc;
#pragma unroll
    for (int q = 0; q < 4; ++q) {
        float4 a = hv[q];
        float4 b4 = w[q];
        acc += a.x * b4.x + a.y * b4.y + a.z * b4.z + a.w * b4.w;
    }
    out[v] = acc;
}

extern "C" void kernel_launch(void* const* d_in, const int* in_sizes, int n_in,
                              void* d_out, int out_size, void* d_ws, size_t ws_size,
                              hipStream_t stream) {
    const float* x   = (const float*)d_in[0];
    const int*   ei  = (const int*)d_in[1];
    const float* Wl0 = (const float*)d_in[2];
    const float* Wr0 = (const float*)d_in[3];
    const float* b0  = (const float*)d_in[4];
    const float* Wl1 = (const float*)d_in[5];
    const float* Wr1 = (const float*)d_in[6];
    const float* b1  = (const float*)d_in[7];
    const float* Wl2 = (const float*)d_in[8];
    const float* Wr2 = (const float*)d_in[9];
    const float* b2  = (const float*)d_in[10];
    const float* Wc  = (const float*)d_in[11];
    const float* bc  = (const float*)d_in[12];
    float* out = (float*)d_out;

    const int N = NN;
    const int E = in_sizes[1] / 2;
    const int* src = ei;
    const int* dst = ei + E;

    char* ws = (char*)d_ws;
    const size_t MB = 1 << 20;
    int*   cnt = (int*)(ws + 0);
    float* inv = (float*)(ws + 1 * MB);
    char*  A   = ws + 2 * MB;   // 26 MB region
    char*  B   = ws + 28 * MB;  // 26 MB region
    // Layer 0: g0 = A, s0 = B, h1 -> A (over g0)
    float* g0 = (float*)A;
    float* s0 = (float*)B;
    float* h1 = (float*)A;
    // Layer 1: g1 = B[0..12.8MB) (over s0), s1 = B+13MB, h2 -> B (over g1)
    float* g1 = (float*)B;
    float* s1 = (float*)(B + 13 * MB);
    float* h2 = (float*)B;
    // Layer 2: g2 = A (over h1), s2 = A+7MB, h3 -> A+14MB
    float* g2 = (float*)A;
    float* s2 = (float*)(A + 7 * MB);
    float* h3 = (float*)(A + 14 * MB);

    // degrees (ws is re-poisoned before every call -> recompute)
    hipMemsetAsync(cnt, 0, (size_t)N * 4, stream);
    count_k<<<2048, 256, 0, stream>>>(dst, E, cnt);
    inv_k<<<(N + 255) / 256, 256, 0, stream>>>(cnt, inv, N);

    // ---- layer 0: 64 -> 64 ----
    transform_k<64, 64><<<(N * 64 + 255) / 256, 256, 0, stream>>>(x, Wl0, g0, N);
    hipMemsetAsync(s0, 0, (size_t)N * 64 * 4, stream);
    scatter_k<64><<<4096, 256, 0, stream>>>(g0, src, dst, E, s0);
    combine_k<64, 64><<<(N * 64 + 255) / 256, 256, 0, stream>>>(s0, inv, x, Wr0, b0, h1, N);

    // ---- layer 1: 64 -> 32 ----
    transform_k<64, 32><<<(N * 32 + 255) / 256, 256, 0, stream>>>(h1, Wl1, g1, N);
    hipMemsetAsync(s1, 0, (size_t)N * 32 * 4, stream);
    scatter_k<32><<<4096, 256, 0, stream>>>(g1, src, dst, E, s1);
    combine_k<64, 32><<<(N * 32 + 255) / 256, 256, 0, stream>>>(s1, inv, h1, Wr1, b1, h2, N);

    // ---- layer 2: 32 -> 16 ----
    transform_k<32, 16><<<(N * 16 + 255) / 256, 256, 0, stream>>>(h2, Wl2, g2, N);
    hipMemsetAsync(s2, 0, (size_t)N * 16 * 4, stream);
    scatter_k<16><<<4096, 256, 0, stream>>>(g2, src, dst, E, s2);
    combine_k<32, 16><<<(N * 16 + 255) / 256, 256, 0, stream>>>(s2, inv, h2, Wr2, b2, h3, N);

    // ---- head: 16 -> 1 ----
    final_k<<<(N + 255) / 256, 256, 0, stream>>>(h3, Wc, bc, out, N);
}

// Round 2
// 1215.714 us; speedup vs baseline: 4.2195x; 4.2195x over previous
//
#include <hip/hip_runtime.h>

// GraphSAGE: 3x SAGEConv(mean) + linear head.
// N=100000 nodes, E=3200000 edges, dims 64 -> 64 -> 32 -> 16 -> 1.
// Round 2: replace fp32 atomic scatter (3.3 GB write traffic/layer) with
// per-call CSR build + pull-style gather aggregation fused with combine.
// agg-linearity: mean(h[src]) @ Wl == mean((h@Wl)[src]) -> transform first.

#define NN 100000

// ---------------- degree count ----------------
__global__ void count_k(const int* __restrict__ dst, int E, int* __restrict__ cnt) {
    int idx = blockIdx.x * blockDim.x + threadIdx.x;
    int stride = gridDim.x * blockDim.x;
    for (int e = idx; e < E; e += stride) atomicAdd(&cnt[dst[e]], 1);
}

__global__ void inv_k(const int* __restrict__ cnt, float* __restrict__ inv, int N) {
    int v = blockIdx.x * blockDim.x + threadIdx.x;
    if (v < N) inv[v] = 1.0f / (float)max(cnt[v], 1);
}

// ---------------- one-block exclusive scan (N=100k) ----------------
__global__ void scan_k(const int* __restrict__ cnt, int* __restrict__ off,
                       int* __restrict__ woff, int N) {
    __shared__ int part[1024];
    int tid = threadIdx.x;
    int chunk = (N + 1023) / 1024;
    int b0 = tid * chunk, e0 = min(b0 + chunk, N);
    int s = 0;
    for (int i = b0; i < e0; ++i) s += cnt[i];
    part[tid] = s;
    __syncthreads();
    // Hillis-Steele inclusive scan
    for (int d = 1; d < 1024; d <<= 1) {
        int t = (tid >= d) ? part[tid - d] : 0;
        __syncthreads();
        part[tid] += t;
        __syncthreads();
    }
    int run = (tid == 0) ? 0 : part[tid - 1];
    for (int i = b0; i < e0; ++i) {
        off[i] = run; woff[i] = run;
        run += cnt[i];
    }
    if (tid == 1023) { off[N] = run; woff[N] = run; }
}

// ---------------- CSR fill: adj[pos] = src, grouped by dst ----------------
__global__ void fill_k(const int* __restrict__ src, const int* __restrict__ dst, int E,
                       int* __restrict__ woff, int* __restrict__ adj) {
    int idx = blockIdx.x * blockDim.x + threadIdx.x;
    int stride = gridDim.x * blockDim.x;
    for (int e = idx; e < E; e += stride) {
        int p = atomicAdd(&woff[dst[e]], 1);
        adj[p] = src[e];
    }
}

// ---------------- g = h @ W  (N x DIN) @ (DIN x DOUT) ----------------
template <int DIN, int DOUT>
__global__ void transform_k(const float* __restrict__ h, const float* __restrict__ W,
                            float* __restrict__ g, int N) {
    __shared__ float sW[DIN * DOUT];
    for (int i = threadIdx.x; i < DIN * DOUT; i += blockDim.x) sW[i] = W[i];
    __syncthreads();
    int idx = blockIdx.x * blockDim.x + threadIdx.x;
    if (idx >= N * DOUT) return;
    int v = idx / DOUT, j = idx % DOUT;
    const float* hv = h + (size_t)v * DIN;
    float acc = 0.f;
#pragma unroll
    for (int k = 0; k < DIN; ++k) acc = fmaf(hv[k], sW[k * DOUT + j], acc);
    g[idx] = acc;
}

// ---------- fused: out = relu( mean-gather(g) + h @ Wr + b ) ----------
// One wave per dst node. Q = DOUT/4 lanes cover a row as float4;
// EPT = 64/Q edges are gathered in parallel -> high MLP, no atomics.
template <int DIN, int DOUT, int WAVES>
__global__ void agg_combine_k(const float* __restrict__ g, const int* __restrict__ off,
                              const int* __restrict__ adj, const float* __restrict__ invc,
                              const float* __restrict__ h, const float* __restrict__ Wr,
                              const float* __restrict__ b, float* __restrict__ out, int N) {
    constexpr int Q = DOUT / 4;   // float4 lanes per node row
    constexpr int EPT = 64 / Q;   // edges in flight per wave
    __shared__ float sW[DIN * DOUT];
    __shared__ float sb[DOUT];
    __shared__ float sh[WAVES][DIN];
    for (int i = threadIdx.x; i < DIN * DOUT; i += blockDim.x) sW[i] = Wr[i];
    if (threadIdx.x < DOUT) sb[threadIdx.x] = b[threadIdx.x];
    int wid = threadIdx.x >> 6, lane = threadIdx.x & 63;
    int v = blockIdx.x * WAVES + wid;
    if (v < N && lane < DIN) sh[wid][lane] = h[(size_t)v * DIN + lane];
    __syncthreads();
    if (v >= N) return;

    int eg = lane / Q, q = lane % Q;
    int beg = off[v], end = off[v + 1];
    float4 acc = make_float4(0.f, 0.f, 0.f, 0.f);
    const float4* g4 = (const float4*)g;
    for (int i = beg; i < end; i += EPT) {
        int e = i + eg;
        if (e < end) {
            int sv = adj[e];
            float4 gv = g4[(size_t)sv * Q + q];
            acc.x += gv.x; acc.y += gv.y; acc.z += gv.z; acc.w += gv.w;
        }
    }
#pragma unroll
    for (int d = Q; d < 64; d <<= 1) {
        acc.x += __shfl_xor(acc.x, d, 64);
        acc.y += __shfl_xor(acc.y, d, 64);
        acc.z += __shfl_xor(acc.z, d, 64);
        acc.w += __shfl_xor(acc.w, d, 64);
    }
    if (eg == 0) {
        float iv = invc[v];
        float o[4];
#pragma unroll
        for (int c = 0; c < 4; ++c) {
            int j = q * 4 + c;
            float a = sb[j];
#pragma unroll
            for (int k = 0; k < DIN; ++k) a = fmaf(sh[wid][k], sW[k * DOUT + j], a);
            o[c] = a;
        }
        float4 r;
        r.x = fmaxf(acc.x * iv + o[0], 0.f);
        r.y = fmaxf(acc.y * iv + o[1], 0.f);
        r.z = fmaxf(acc.z * iv + o[2], 0.f);
        r.w = fmaxf(acc.w * iv + o[3], 0.f);
        ((float4*)out)[(size_t)v * Q + q] = r;
    }
}

// ---------------- head: out = h3 @ Wc + bc (16 -> 1) ----------------
__global__ void final_k(const float* __restrict__ h, const float* __restrict__ Wc,
                        const float* __restrict__ bc, float* __restrict__ out, int N) {
    int v = blockIdx.x * blockDim.x + threadIdx.x;
    if (v >= N) return;
    float acc = bc[0];
    const float4* hv = (const float4*)(h + (size_t)v * 16);
    const float4* w = (const float4*)Wc;
#pragma unroll
    for (int q = 0; q < 4; ++q) {
        float4 a = hv[q];
        float4 b4 = w[q];
        acc += a.x * b4.x + a.y * b4.y + a.z * b4.z + a.w * b4.w;
    }
    out[v] = acc;
}

extern "C" void kernel_launch(void* const* d_in, const int* in_sizes, int n_in,
                              void* d_out, int out_size, void* d_ws, size_t ws_size,
                              hipStream_t stream) {
    const float* x   = (const float*)d_in[0];
    const int*   ei  = (const int*)d_in[1];
    const float* Wl0 = (const float*)d_in[2];
    const float* Wr0 = (const float*)d_in[3];
    const float* b0  = (const float*)d_in[4];
    const float* Wl1 = (const float*)d_in[5];
    const float* Wr1 = (const float*)d_in[6];
    const float* b1  = (const float*)d_in[7];
    const float* Wl2 = (const float*)d_in[8];
    const float* Wr2 = (const float*)d_in[9];
    const float* b2  = (const float*)d_in[10];
    const float* Wc  = (const float*)d_in[11];
    const float* bc  = (const float*)d_in[12];
    float* out = (float*)d_out;

    const int N = NN;
    const int E = in_sizes[1] / 2;
    const int* src = ei;
    const int* dst = ei + E;

    char* ws = (char*)d_ws;
    const size_t MB = 1 << 20;
    int*   cnt  = (int*)(ws + 0);
    int*   off  = (int*)(ws + (MB / 2));
    int*   woff = (int*)(ws + 1 * MB);
    float* inv  = (float*)(ws + 3 * MB / 2);
    int*   adj  = (int*)(ws + 2 * MB);          // 12.8 MB
    char*  G    = ws + 15 * MB;                 // 26 MB region
    char*  A    = ws + 41 * MB;                 // 26 MB region (ends at 67 MB)

    float* g0 = (float*)G;                      // 25.6 MB
    float* h1 = (float*)A;                      // 25.6 MB
    float* g1 = (float*)G;                      // 12.8 MB
    float* h2 = (float*)(G + 13 * MB);          // 12.8 MB (g0's dead upper half)
    float* g2 = (float*)A;                      // 6.4 MB (h1 dead by then)
    float* h3 = (float*)(A + 7 * MB);           // 6.4 MB

    // ---- CSR build (ws re-poisoned every call -> rebuild) ----
    hipMemsetAsync(cnt, 0, (size_t)N * 4, stream);
    count_k<<<1024, 256, 0, stream>>>(dst, E, cnt);
    scan_k<<<1, 1024, 0, stream>>>(cnt, off, woff, N);
    inv_k<<<(N + 255) / 256, 256, 0, stream>>>(cnt, inv, N);
    fill_k<<<2048, 256, 0, stream>>>(src, dst, E, woff, adj);

    // ---- layer 0: 64 -> 64 ----
    transform_k<64, 64><<<(N * 64 + 255) / 256, 256, 0, stream>>>(x, Wl0, g0, N);
    agg_combine_k<64, 64, 4><<<(N + 3) / 4, 256, 0, stream>>>(g0, off, adj, inv, x, Wr0, b0, h1, N);

    // ---- layer 1: 64 -> 32 ----
    transform_k<64, 32><<<(N * 32 + 255) / 256, 256, 0, stream>>>(h1, Wl1, g1, N);
    agg_combine_k<64, 32, 4><<<(N + 3) / 4, 256, 0, stream>>>(g1, off, adj, inv, h1, Wr1, b1, h2, N);

    // ---- layer 2: 32 -> 16 ----
    transform_k<32, 16><<<(N * 16 + 255) / 256, 256, 0, stream>>>(h2, Wl2, g2, N);
    agg_combine_k<32, 16, 4><<<(N + 3) / 4, 256, 0, stream>>>(g2, off, adj, inv, h2, Wr2, b2, h3, N);

    // ---- head: 16 -> 1 ----
    final_k<<<(N + 255) / 256, 256, 0, stream>>>(h3, Wc, bc, out, N);
}